// Round 9
// baseline (308.921 us; speedup 1.0000x reference)
//
#include <hip/hip_runtime.h>

typedef unsigned short ushort_t;
typedef unsigned int uint_t;
typedef __attribute__((ext_vector_type(4))) float f32x4;
typedef __attribute__((ext_vector_type(8))) __bf16 bf16x8;

#define LAMBDA_INIT 0.7836057665316245f
#define ONE_MINUS_LI 0.21639423346837552f
#define QSCALE_LOG2E 0.25505654442552663f  // 32^-0.5 * log2(e)

__device__ inline ushort_t f2bf(float f) {
  union { float f; unsigned u; } v; v.f = f;
  unsigned r = (v.u + 0x7FFFu + ((v.u >> 16) & 1u)) >> 16;
  return (ushort_t)r;
}

// bare v_exp_f32 (args bounded, no libm range fixup needed)
__device__ inline float fexp2(float x) {
  float r;
  asm("v_exp_f32 %0, %1" : "=v"(r) : "v"(x));
  return r;
}

// pack 2 f32 -> 2 bf16 (RNE), lo in low half
__device__ inline uint_t cvtpk(float lo, float hi) {
  uint_t r;
  asm("v_cvt_pk_bf16_f32 %0, %1, %2" : "=v"(r) : "v"(lo), "v"(hi));
  return r;
}

__device__ inline f32x4 zero4() { f32x4 z = {0.f, 0.f, 0.f, 0.f}; return z; }

__device__ inline f32x4 mfma16(bf16x8 a, bf16x8 b, f32x4 c) {
  return __builtin_amdgcn_mfma_f32_16x16x32_bf16(a, b, c, 0, 0, 0);
}

__device__ inline void gload_lds16(const void* g, void* l) {
  __builtin_amdgcn_global_load_lds(
      (const __attribute__((address_space(1))) unsigned int*)g,
      (__attribute__((address_space(3))) unsigned int*)l, 16, 0, 0);
}

// ---------------- convert x (fp32 -> bf16) ----------------
__global__ __launch_bounds__(256) void cvt_f32_bf16(const float* __restrict__ in,
                                                    ushort_t* __restrict__ out, int n) {
  int i = (blockIdx.x * 256 + threadIdx.x) * 8;
  if (i >= n) return;
  float4 a = *(const float4*)(in + i);
  float4 b = *(const float4*)(in + i + 4);
  uint4 pack;
  pack.x = cvtpk(a.x, a.y);
  pack.y = cvtpk(a.z, a.w);
  pack.z = cvtpk(b.x, b.y);
  pack.w = cvtpk(b.z, b.w);
  *(uint4*)(out + i) = pack;
}

// ---------------- transpose W (KxN fp32) -> WT (NxK bf16) ----------------
__global__ __launch_bounds__(256) void transpose_to_bf16(const float* __restrict__ W,
                                                         ushort_t* __restrict__ WT,
                                                         int K, int N) {
  __shared__ float tile[32][33];
  int n0 = blockIdx.x * 32, k0 = blockIdx.y * 32;
  int tx = threadIdx.x & 31, ty = threadIdx.x >> 5;
#pragma unroll
  for (int j = 0; j < 4; ++j) {
    int k = k0 + ty + j * 8;
    tile[ty + j * 8][tx] = W[(size_t)k * N + n0 + tx];
  }
  __syncthreads();
#pragma unroll
  for (int j = 0; j < 4; ++j) {
    int n = n0 + ty + j * 8;
    WT[(size_t)n * K + k0 + tx] = f2bf(tile[tx][ty + j * 8]);
  }
}

// ---------------- GEMM: C[M,N] = A[M,K] * Bt[N,K]^T, bf16 in ----------------
template <int MODE>
__global__ __launch_bounds__(256) void gemm_bt(const ushort_t* __restrict__ A,
                                               const ushort_t* __restrict__ Bt,
                                               void* __restrict__ C,
                                               ushort_t* __restrict__ vt_out,
                                               const float* __restrict__ bias,
                                               int M, int N, int K) {
  __shared__ ushort_t As[128 * 32];
  __shared__ ushort_t Bs[128 * 32];
  const int tid = threadIdx.x;
  const int wave = tid >> 6, lane = tid & 63;
  const int wr = wave >> 1, wc = wave & 1;
  const int lg = lane >> 4, ll = lane & 15;
  const int row0 = blockIdx.x * 128, col0 = blockIdx.y * 128;

  f32x4 acc[4][4];
#pragma unroll
  for (int m = 0; m < 4; ++m)
#pragma unroll
    for (int n = 0; n < 4; ++n) acc[m][n] = zero4();

  for (int k0 = 0; k0 < K; k0 += 32) {
    __syncthreads();
#pragma unroll
    for (int i = 0; i < 2; ++i) {
      int c = tid + i * 256;
      int r = c >> 2, ko = (c & 3) << 3;
      gload_lds16(A + (size_t)(row0 + r) * K + k0 + ko,
                  (char*)As + (size_t)(wave * 64 + i * 256) * 16);
      gload_lds16(Bt + (size_t)(col0 + r) * K + k0 + ko,
                  (char*)Bs + (size_t)(wave * 64 + i * 256) * 16);
    }
    __syncthreads();
    bf16x8 af[4], bf[4];
#pragma unroll
    for (int m = 0; m < 4; ++m)
      af[m] = *(const bf16x8*)(As + (wr * 64 + m * 16 + ll) * 32 + (lg << 3));
#pragma unroll
    for (int n = 0; n < 4; ++n)
      bf[n] = *(const bf16x8*)(Bs + (wc * 64 + n * 16 + ll) * 32 + (lg << 3));
#pragma unroll
    for (int m = 0; m < 4; ++m)
#pragma unroll
      for (int n = 0; n < 4; ++n) acc[m][n] = mfma16(af[m], bf[n], acc[m][n]);
  }

#pragma unroll
  for (int m = 0; m < 4; ++m) {
#pragma unroll
    for (int n = 0; n < 4; ++n) {
      int gc = col0 + wc * 64 + n * 16 + ll;
      int gr0 = row0 + wr * 64 + m * 16 + (lg << 2);
      if (MODE == 0) {
#pragma unroll
        for (int j = 0; j < 4; ++j)
          ((float*)C)[(size_t)(gr0 + j) * N + gc] = acc[m][n][j] + bias[gc];
      } else {
        if (gc < 2048) {
          float sc = (gc < 1024) ? QSCALE_LOG2E : 1.0f;
#pragma unroll
          for (int j = 0; j < 4; ++j)
            ((ushort_t*)C)[(size_t)(gr0 + j) * 2048 + gc] = f2bf(acc[m][n][j] * sc);
        } else {
          // V columns -> transposed store, 4 consecutive n packed into 8B
          int hv = (gc - 2048) >> 6, dv = (gc - 2048) & 63;
          int bb = gr0 >> 11, nn = gr0 & 2047;
          uint2 w;
          w.x = cvtpk(acc[m][n][0], acc[m][n][1]);
          w.y = cvtpk(acc[m][n][2], acc[m][n][3]);
          *(uint2*)(vt_out + ((size_t)((bb * 16 + hv) * 64 + dv)) * 2048 + nn) = w;
        }
      }
    }
  }
}

// ---------------- differential flash attention (no-staging variant) ----------------
// Swapped QK^T + static max (proven R4 math, byte-identical P path: affine
// stride-72, uint2 write / bf16x8 read, in-order per-wave DS). K/V fragments
// load DIRECTLY from global (panels are L2-resident, 256KB per (b,h), reused
// by 32 qt-blocks) -> no LDS staging, no double-buffer, ZERO barriers in the
// main loop; every wave runs independently.
__global__ __launch_bounds__(256) void diff_attn(const ushort_t* __restrict__ qk,
                                                 const ushort_t* __restrict__ vt,
                                                 ushort_t* __restrict__ o,
                                                 const float* __restrict__ lq1,
                                                 const float* __restrict__ lk1,
                                                 const float* __restrict__ lq2,
                                                 const float* __restrict__ lk2,
                                                 const float* __restrict__ subln) {
  const int qt = blockIdx.x, h = blockIdx.y, b = blockIdx.z;
  const int tid = threadIdx.x, wave = tid >> 6, lane = tid & 63;
  const int lg = lane >> 4, ll = lane & 15;

  const size_t qbase = (size_t)b * 2048 * 2048;
  const int cq1 = (h << 5), cq2 = 512 + (h << 5);
  const int ck1 = 1024 + (h << 5), ck2 = 1536 + (h << 5);
  const size_t vbase = (size_t)((b * 16 + h) * 64) * 2048;

  float sl1 = 0.f, sl2 = 0.f;
  for (int j = 0; j < 32; ++j) { sl1 += lq1[j] * lk1[j]; sl2 += lq2[j] * lk2[j]; }
  const float lam = __expf(sl1) - __expf(sl2) + LAMBDA_INIT;

  __shared__ ushort_t Pl[4][16 * 72];   // per-wave P, padded stride 72 (proven R4 layout)

  // Q fragments (B-operand of swapped QK^T)
  const int qrow = qt * 64 + wave * 16 + ll;
  const bf16x8 q1f = *(const bf16x8*)(qk + qbase + (size_t)qrow * 2048 + cq1 + (lg << 3));
  const bf16x8 q2f = *(const bf16x8*)(qk + qbase + (size_t)qrow * 2048 + cq2 + (lg << 3));

  f32x4 o1[4], o2[4];
#pragma unroll
  for (int nb = 0; nb < 4; ++nb) { o1[nb] = zero4(); o2[nb] = zero4(); }
  float l1p = 0.f, l2p = 0.f;
  ushort_t* Pw = &Pl[wave][0];

  // per-lane fragment bases (row = +ll everywhere; col offset = lg*8 ushorts)
  const ushort_t* kbase = qk + qbase + (size_t)ll * 2048 + (lg << 3);
  const ushort_t* vbase_p = vt + vbase + (size_t)ll * 2048 + (lg << 3);

  for (int kv0 = 0; kv0 < 2048; kv0 += 64) {
    // K fragments, both maps (rows kv0 + nb*16 + ll)
    bf16x8 kf1[4], kf2[4], vf[2][4];
#pragma unroll
    for (int nb = 0; nb < 4; ++nb) {
      const ushort_t* krow = kbase + (size_t)(kv0 + nb * 16) * 2048;
      kf1[nb] = *(const bf16x8*)(krow + ck1);
      kf2[nb] = *(const bf16x8*)(krow + ck2);
    }
    // V^T fragments (rows d = nb*16 + ll, cols kv0 + ks*32 + lg*8)
#pragma unroll
    for (int ks = 0; ks < 2; ++ks)
#pragma unroll
      for (int nb = 0; nb < 4; ++nb)
        vf[ks][nb] = *(const bf16x8*)(vbase_p + (size_t)(nb * 16) * 2048 + kv0 + (ks << 5));

#pragma unroll
    for (int pass = 0; pass < 2; ++pass) {
      const bf16x8 qf = pass ? q2f : q1f;
      const bf16x8* kf = pass ? kf2 : kf1;
      f32x4* oacc = pass ? o2 : o1;
      f32x4 s[4];
#pragma unroll
      for (int nb = 0; nb < 4; ++nb)
        s[nb] = mfma16(kf[nb], qf, zero4());   // D: row=k (4lg+i), col=q (ll)
      float part = 0.f;
#pragma unroll
      for (int nb = 0; nb < 4; ++nb) {
        float e0 = fexp2(s[nb][0]), e1 = fexp2(s[nb][1]);
        float e2 = fexp2(s[nb][2]), e3 = fexp2(s[nb][3]);
        part += (e0 + e1) + (e2 + e3);
        uint2 w;
        w.x = cvtpk(e0, e1);
        w.y = cvtpk(e2, e3);
        // P[q=ll][k = nb*16 + 4lg .. +3]
        *(uint2*)(Pw + ll * 72 + nb * 16 + (lg << 2)) = w;
      }
      if (pass) l2p += part; else l1p += part;
#pragma unroll
      for (int ks = 0; ks < 2; ++ks) {
        bf16x8 pf = *(const bf16x8*)(Pw + ll * 72 + ks * 32 + (lg << 3));
#pragma unroll
        for (int nb = 0; nb < 4; ++nb) oacc[nb] = mfma16(pf, vf[ks][nb], oacc[nb]);
      }
    }
  }

  // l lives per-lane for q = ll; finish reduction over lg, then fetch per-row.
  float l1 = l1p; l1 += __shfl_xor(l1, 16); l1 += __shfl_xor(l1, 32);
  float l2 = l2p; l2 += __shfl_xor(l2, 16); l2 += __shfl_xor(l2, 32);
  float i1[4], i2[4];
#pragma unroll
  for (int j = 0; j < 4; ++j) {
    int src = (lane & 48) | ((lg << 2) + j);   // lane with ll == q-row
    i1[j] = 1.f / __shfl(l1, src);
    i2[j] = 1.f / __shfl(l2, src);
  }

  float ss[4] = {0.f, 0.f, 0.f, 0.f};
  f32x4 ov[4];
#pragma unroll
  for (int nb = 0; nb < 4; ++nb) {
#pragma unroll
    for (int j = 0; j < 4; ++j) {
      float x = o1[nb][j] * i1[j] - lam * (o2[nb][j] * i2[j]);
      ov[nb][j] = x;
      ss[j] += x * x;
    }
  }
#pragma unroll
  for (int mask = 1; mask < 16; mask <<= 1)
#pragma unroll
    for (int j = 0; j < 4; ++j) ss[j] += __shfl_xor(ss[j], mask);
  float nf[4];
#pragma unroll
  for (int j = 0; j < 4; ++j) nf[j] = rsqrtf(ss[j] * (1.f / 64.f) + 1e-5f);
  const size_t orow0 = (size_t)(b * 2048 + qt * 64 + wave * 16);
#pragma unroll
  for (int nb = 0; nb < 4; ++nb) {
    int d = nb * 16 + ll;
    float sw = subln[d] * ONE_MINUS_LI;
#pragma unroll
    for (int j = 0; j < 4; ++j) {
      int r = (lg << 2) + j;
      o[(orow0 + r) * 1024 + (h << 6) + d] = f2bf(ov[nb][j] * nf[j] * sw);
    }
  }
}

extern "C" void kernel_launch(void* const* d_in, const int* in_sizes, int n_in,
                              void* d_out, int out_size, void* d_ws, size_t ws_size,
                              hipStream_t stream) {
  const float* x      = (const float*)d_in[0];
  const float* W_qkv  = (const float*)d_in[1];
  const float* W_proj = (const float*)d_in[2];
  const float* b_proj = (const float*)d_in[3];
  const float* lq1    = (const float*)d_in[4];
  const float* lk1    = (const float*)d_in[5];
  const float* lq2    = (const float*)d_in[6];
  const float* lk2    = (const float*)d_in[7];
  const float* subln  = (const float*)d_in[8];

  char* ws = (char*)d_ws;
  ushort_t* xb     = (ushort_t*)(ws);                 //  8,388,608 B (4096x1024 bf16)
  ushort_t* qkb    = (ushort_t*)(ws + 8388608);       // 16,777,216 B (4096x2048 bf16, q|k)
  ushort_t* vtb    = (ushort_t*)(ws + 25165824);      //  8,388,608 B (V^T: [2*16*64][2048])
  ushort_t* wqkvT  = (ushort_t*)(ws + 33554432);      //  6,291,456 B (3072x1024 bf16)
  ushort_t* wprojT = (ushort_t*)(ws + 39845888);      //  2,097,152 B (1024x1024 bf16)
  ushort_t* ob     = (ushort_t*)(ws + 41943040);      //  8,388,608 B (4096x1024 bf16)

  cvt_f32_bf16<<<2048, 256, 0, stream>>>(x, xb, 4096 * 1024);
  transpose_to_bf16<<<dim3(96, 32), 256, 0, stream>>>(W_qkv, wqkvT, 1024, 3072);
  transpose_to_bf16<<<dim3(32, 32), 256, 0, stream>>>(W_proj, wprojT, 1024, 1024);
  gemm_bt<1><<<dim3(32, 24), 256, 0, stream>>>(xb, wqkvT, (void*)qkb, vtb, nullptr, 4096, 3072, 1024);
  diff_attn<<<dim3(32, 16, 2), 256, 0, stream>>>(qkb, vtb, ob, lq1, lk1, lq2, lk2, subln);
  gemm_bt<0><<<dim3(32, 8), 256, 0, stream>>>(ob, wprojT, d_out, nullptr, b_proj, 4096, 1024, 1024);
}

// Round 10
// 205.820 us; speedup vs baseline: 1.5009x; 1.5009x over previous
//
#include <hip/hip_runtime.h>

typedef unsigned short ushort_t;
typedef unsigned int uint_t;
typedef __attribute__((ext_vector_type(4))) float f32x4;
typedef __attribute__((ext_vector_type(8))) __bf16 bf16x8;

#define LAMBDA_INIT 0.7836057665316245f
#define ONE_MINUS_LI 0.21639423346837552f
#define QSCALE_LOG2E 0.25505654442552663f  // 32^-0.5 * log2(e)

__device__ inline ushort_t f2bf(float f) {
  union { float f; unsigned u; } v; v.f = f;
  unsigned r = (v.u + 0x7FFFu + ((v.u >> 16) & 1u)) >> 16;
  return (ushort_t)r;
}

// bare v_exp_f32 (args bounded, no libm range fixup needed)
__device__ inline float fexp2(float x) {
  float r;
  asm("v_exp_f32 %0, %1" : "=v"(r) : "v"(x));
  return r;
}

// pack 2 f32 -> 2 bf16 (RNE), lo in low half
__device__ inline uint_t cvtpk(float lo, float hi) {
  uint_t r;
  asm("v_cvt_pk_bf16_f32 %0, %1, %2" : "=v"(r) : "v"(lo), "v"(hi));
  return r;
}

__device__ inline f32x4 zero4() { f32x4 z = {0.f, 0.f, 0.f, 0.f}; return z; }

__device__ inline f32x4 mfma16(bf16x8 a, bf16x8 b, f32x4 c) {
  return __builtin_amdgcn_mfma_f32_16x16x32_bf16(a, b, c, 0, 0, 0);
}

__device__ inline void gload_lds16(const void* g, void* l) {
  __builtin_amdgcn_global_load_lds(
      (const __attribute__((address_space(1))) unsigned int*)g,
      (__attribute__((address_space(3))) unsigned int*)l, 16, 0, 0);
}

// ---------------- convert x (fp32 -> bf16) ----------------
__global__ __launch_bounds__(256) void cvt_f32_bf16(const float* __restrict__ in,
                                                    ushort_t* __restrict__ out, int n) {
  int i = (blockIdx.x * 256 + threadIdx.x) * 8;
  if (i >= n) return;
  float4 a = *(const float4*)(in + i);
  float4 b = *(const float4*)(in + i + 4);
  uint4 pack;
  pack.x = cvtpk(a.x, a.y);
  pack.y = cvtpk(a.z, a.w);
  pack.z = cvtpk(b.x, b.y);
  pack.w = cvtpk(b.z, b.w);
  *(uint4*)(out + i) = pack;
}

// ---------------- transpose W (KxN fp32) -> WT (NxK bf16) ----------------
__global__ __launch_bounds__(256) void transpose_to_bf16(const float* __restrict__ W,
                                                         ushort_t* __restrict__ WT,
                                                         int K, int N) {
  __shared__ float tile[32][33];
  int n0 = blockIdx.x * 32, k0 = blockIdx.y * 32;
  int tx = threadIdx.x & 31, ty = threadIdx.x >> 5;
#pragma unroll
  for (int j = 0; j < 4; ++j) {
    int k = k0 + ty + j * 8;
    tile[ty + j * 8][tx] = W[(size_t)k * N + n0 + tx];
  }
  __syncthreads();
#pragma unroll
  for (int j = 0; j < 4; ++j) {
    int n = n0 + ty + j * 8;
    WT[(size_t)n * K + k0 + tx] = f2bf(tile[tx][ty + j * 8]);
  }
}

// ---------------- GEMM: C[M,N] = A[M,K] * Bt[N,K]^T, bf16 in ----------------
template <int MODE>
__global__ __launch_bounds__(256) void gemm_bt(const ushort_t* __restrict__ A,
                                               const ushort_t* __restrict__ Bt,
                                               void* __restrict__ C,
                                               ushort_t* __restrict__ vt_out,
                                               const float* __restrict__ bias,
                                               int M, int N, int K) {
  __shared__ ushort_t As[128 * 32];
  __shared__ ushort_t Bs[128 * 32];
  const int tid = threadIdx.x;
  const int wave = tid >> 6, lane = tid & 63;
  const int wr = wave >> 1, wc = wave & 1;
  const int lg = lane >> 4, ll = lane & 15;
  const int row0 = blockIdx.x * 128, col0 = blockIdx.y * 128;

  f32x4 acc[4][4];
#pragma unroll
  for (int m = 0; m < 4; ++m)
#pragma unroll
    for (int n = 0; n < 4; ++n) acc[m][n] = zero4();

  for (int k0 = 0; k0 < K; k0 += 32) {
    __syncthreads();
#pragma unroll
    for (int i = 0; i < 2; ++i) {
      int c = tid + i * 256;
      int r = c >> 2, ko = (c & 3) << 3;
      gload_lds16(A + (size_t)(row0 + r) * K + k0 + ko,
                  (char*)As + (size_t)(wave * 64 + i * 256) * 16);
      gload_lds16(Bt + (size_t)(col0 + r) * K + k0 + ko,
                  (char*)Bs + (size_t)(wave * 64 + i * 256) * 16);
    }
    __syncthreads();
    bf16x8 af[4], bf[4];
#pragma unroll
    for (int m = 0; m < 4; ++m)
      af[m] = *(const bf16x8*)(As + (wr * 64 + m * 16 + ll) * 32 + (lg << 3));
#pragma unroll
    for (int n = 0; n < 4; ++n)
      bf[n] = *(const bf16x8*)(Bs + (wc * 64 + n * 16 + ll) * 32 + (lg << 3));
#pragma unroll
    for (int m = 0; m < 4; ++m)
#pragma unroll
      for (int n = 0; n < 4; ++n) acc[m][n] = mfma16(af[m], bf[n], acc[m][n]);
  }

#pragma unroll
  for (int m = 0; m < 4; ++m) {
#pragma unroll
    for (int n = 0; n < 4; ++n) {
      int gc = col0 + wc * 64 + n * 16 + ll;
      int gr0 = row0 + wr * 64 + m * 16 + (lg << 2);
      if (MODE == 0) {
#pragma unroll
        for (int j = 0; j < 4; ++j)
          ((float*)C)[(size_t)(gr0 + j) * N + gc] = acc[m][n][j] + bias[gc];
      } else {
        if (gc < 2048) {
          float sc = (gc < 1024) ? QSCALE_LOG2E : 1.0f;
#pragma unroll
          for (int j = 0; j < 4; ++j)
            ((ushort_t*)C)[(size_t)(gr0 + j) * 2048 + gc] = f2bf(acc[m][n][j] * sc);
        } else {
          // V columns -> transposed store, 4 consecutive n packed into 8B
          int hv = (gc - 2048) >> 6, dv = (gc - 2048) & 63;
          int bb = gr0 >> 11, nn = gr0 & 2047;
          uint2 w;
          w.x = cvtpk(acc[m][n][0], acc[m][n][1]);
          w.y = cvtpk(acc[m][n][2], acc[m][n][3]);
          *(uint2*)(vt_out + ((size_t)((bb * 16 + hv) * 64 + dv)) * 2048 + nn) = w;
        }
      }
    }
  }
}

// ---------------- differential flash attention (KVBLK=32, swapped-QK, static max, dbuf) ----------------
// Proven R4 structure with halved KV tiles: LDS 20992 B -> grid-limited 4
// blocks/CU (16 waves, 50% cap) instead of LDS-limited 3. P path is the
// R4-proven affine uint2-write / bf16x8-read (stride 36). K staging keeps the
// identical XOR-8 involution; V^T packs two d-rows per 128B LDS row, XOR-8.
__global__ __launch_bounds__(256) void diff_attn(const ushort_t* __restrict__ qk,
                                                 const ushort_t* __restrict__ vt,
                                                 ushort_t* __restrict__ o,
                                                 const float* __restrict__ lq1,
                                                 const float* __restrict__ lk1,
                                                 const float* __restrict__ lq2,
                                                 const float* __restrict__ lk2,
                                                 const float* __restrict__ subln) {
  const int qt = blockIdx.x, h = blockIdx.y, b = blockIdx.z;
  const int tid = threadIdx.x, wave = tid >> 6, lane = tid & 63;
  const int lg = lane >> 4, ll = lane & 15;

  const size_t qbase = (size_t)b * 2048 * 2048;
  const int cq1 = (h << 5), cq2 = 512 + (h << 5);
  const int ck1 = 1024 + (h << 5), ck2 = 1536 + (h << 5);
  const size_t vbase = (size_t)((b * 16 + h) * 64) * 2048;

  float sl1 = 0.f, sl2 = 0.f;
  for (int j = 0; j < 32; ++j) { sl1 += lq1[j] * lk1[j]; sl2 += lq2[j] * lk2[j]; }
  const float lam = __expf(sl1) - __expf(sl2) + LAMBDA_INIT;

  __shared__ ushort_t Ks[2][32 * 64];   // [kv r 0..31][8 chunks: 0-3 K1, 4-7 K2], XOR-8
  __shared__ ushort_t Vs[2][32 * 64];   // [R=d>>1][8 chunks: d-even 0-3, d-odd 4-7], XOR-8
  __shared__ ushort_t Pl[4][16 * 36];   // per-wave P, affine stride 36 (32 k + 4 pad)

  // Q fragments (B-operand of swapped QK^T)
  const int qrow = qt * 64 + wave * 16 + ll;
  const bf16x8 q1f = *(const bf16x8*)(qk + qbase + (size_t)qrow * 2048 + cq1 + (lg << 3));
  const bf16x8 q2f = *(const bf16x8*)(qk + qbase + (size_t)qrow * 2048 + cq2 + (lg << 3));

  f32x4 o1[4], o2[4];
#pragma unroll
  for (int nb = 0; nb < 4; ++nb) { o1[nb] = zero4(); o2[nb] = zero4(); }
  float l1p = 0.f, l2p = 0.f;
  ushort_t* Pw = &Pl[wave][0];

  // staging: 256 threads, one 16B K-slot + one 16B V-slot each.
  // K: slot t -> row r=t>>3, LDS chunk t&7 holds global chunk (t&7)^(r&7).
  const int rk = tid >> 3, ckg = (tid & 7) ^ (rk & 7);
  const int kcol = ((ckg & 4) ? ck2 : ck1) + ((ckg & 3) << 3);
  // V: slot t -> row R=t>>3, global chunk c=(t&7)^(R&7): d=2R+(c>>2), colchunk=c&3.
  const int cvg = (tid & 7) ^ (rk & 7);
  const int vd = 2 * rk + (cvg >> 2), vcol = (cvg & 3) << 3;

#define STAGE(buf, kv0)                                                                  \
  do {                                                                                   \
    gload_lds16(qk + qbase + (size_t)((kv0) + rk) * 2048 + kcol, (char*)Ks[buf] + (tid << 4)); \
    gload_lds16(vt + vbase + (size_t)vd * 2048 + (kv0) + vcol, (char*)Vs[buf] + (tid << 4));   \
  } while (0)

  auto compute_tile = [&](const ushort_t* Kc, const ushort_t* Vc) {
    // V^T fragments: d = nb*16+ll, cols lg*8..+7 -> row nb*8+(ll>>1),
    // chunk (((ll&1)<<2)|lg) ^ (ll>>1)
    bf16x8 vf[4];
#pragma unroll
    for (int nb = 0; nb < 4; ++nb)
      vf[nb] = *(const bf16x8*)(Vc + (nb * 8 + (ll >> 1)) * 64 +
                                (((((ll & 1) << 2) | lg) ^ (ll >> 1)) << 3));
#pragma unroll
    for (int pass = 0; pass < 2; ++pass) {
      const int cK = ((pass << 2) | lg) ^ (ll & 7);
      bf16x8 kf[2];
#pragma unroll
      for (int nb = 0; nb < 2; ++nb)
        kf[nb] = *(const bf16x8*)(Kc + (nb * 16 + ll) * 64 + (cK << 3));
      const bf16x8 qf = pass ? q2f : q1f;
      f32x4* oacc = pass ? o2 : o1;
      f32x4 s[2];
#pragma unroll
      for (int nb = 0; nb < 2; ++nb)
        s[nb] = mfma16(kf[nb], qf, zero4());   // D: row=k (4lg+i), col=q (ll)
      float part = 0.f;
#pragma unroll
      for (int nb = 0; nb < 2; ++nb) {
        float e0 = fexp2(s[nb][0]), e1 = fexp2(s[nb][1]);
        float e2 = fexp2(s[nb][2]), e3 = fexp2(s[nb][3]);
        part += (e0 + e1) + (e2 + e3);
        uint2 w;
        w.x = cvtpk(e0, e1);
        w.y = cvtpk(e2, e3);
        // P[q=ll][k = nb*16 + 4lg .. +3]
        *(uint2*)(Pw + ll * 36 + nb * 16 + (lg << 2)) = w;
      }
      if (pass) l2p += part; else l1p += part;
      // P[q=ll][k = 8lg .. +7] (full K=32 row in one fragment)
      bf16x8 pf = *(const bf16x8*)(Pw + ll * 36 + (lg << 3));
#pragma unroll
      for (int nb = 0; nb < 4; ++nb) oacc[nb] = mfma16(pf, vf[nb], oacc[nb]);
    }
  };

  STAGE(0, 0);
  __syncthreads();
  for (int tt = 0; tt < 32; ++tt) {
    STAGE(1, (tt * 2 + 1) * 32);
    compute_tile(Ks[0], Vs[0]);
    __syncthreads();
    if (tt < 31) STAGE(0, (tt * 2 + 2) * 32);
    compute_tile(Ks[1], Vs[1]);
    __syncthreads();
  }
#undef STAGE

  // l lives per-lane for q = ll; finish reduction over lg, then fetch per-row.
  float l1 = l1p; l1 += __shfl_xor(l1, 16); l1 += __shfl_xor(l1, 32);
  float l2 = l2p; l2 += __shfl_xor(l2, 16); l2 += __shfl_xor(l2, 32);
  float i1[4], i2[4];
#pragma unroll
  for (int j = 0; j < 4; ++j) {
    int src = (lane & 48) | ((lg << 2) + j);   // lane with ll == q-row
    i1[j] = 1.f / __shfl(l1, src);
    i2[j] = 1.f / __shfl(l2, src);
  }

  float ss[4] = {0.f, 0.f, 0.f, 0.f};
  f32x4 ov[4];
#pragma unroll
  for (int nb = 0; nb < 4; ++nb) {
#pragma unroll
    for (int j = 0; j < 4; ++j) {
      float x = o1[nb][j] * i1[j] - lam * (o2[nb][j] * i2[j]);
      ov[nb][j] = x;
      ss[j] += x * x;
    }
  }
#pragma unroll
  for (int mask = 1; mask < 16; mask <<= 1)
#pragma unroll
    for (int j = 0; j < 4; ++j) ss[j] += __shfl_xor(ss[j], mask);
  float nf[4];
#pragma unroll
  for (int j = 0; j < 4; ++j) nf[j] = rsqrtf(ss[j] * (1.f / 64.f) + 1e-5f);
  const size_t orow0 = (size_t)(b * 2048 + qt * 64 + wave * 16);
#pragma unroll
  for (int nb = 0; nb < 4; ++nb) {
    int d = nb * 16 + ll;
    float sw = subln[d] * ONE_MINUS_LI;
#pragma unroll
    for (int j = 0; j < 4; ++j) {
      int r = (lg << 2) + j;
      o[(orow0 + r) * 1024 + (h << 6) + d] = f2bf(ov[nb][j] * nf[j] * sw);
    }
  }
}

extern "C" void kernel_launch(void* const* d_in, const int* in_sizes, int n_in,
                              void* d_out, int out_size, void* d_ws, size_t ws_size,
                              hipStream_t stream) {
  const float* x      = (const float*)d_in[0];
  const float* W_qkv  = (const float*)d_in[1];
  const float* W_proj = (const float*)d_in[2];
  const float* b_proj = (const float*)d_in[3];
  const float* lq1    = (const float*)d_in[4];
  const float* lk1    = (const float*)d_in[5];
  const float* lq2    = (const float*)d_in[6];
  const float* lk2    = (const float*)d_in[7];
  const float* subln  = (const float*)d_in[8];

  char* ws = (char*)d_ws;
  ushort_t* xb     = (ushort_t*)(ws);                 //  8,388,608 B (4096x1024 bf16)
  ushort_t* qkb    = (ushort_t*)(ws + 8388608);       // 16,777,216 B (4096x2048 bf16, q|k)
  ushort_t* vtb    = (ushort_t*)(ws + 25165824);      //  8,388,608 B (V^T: [2*16*64][2048])
  ushort_t* wqkvT  = (ushort_t*)(ws + 33554432);      //  6,291,456 B (3072x1024 bf16)
  ushort_t* wprojT = (ushort_t*)(ws + 39845888);      //  2,097,152 B (1024x1024 bf16)
  ushort_t* ob     = (ushort_t*)(ws + 41943040);      //  8,388,608 B (4096x1024 bf16)

  cvt_f32_bf16<<<2048, 256, 0, stream>>>(x, xb, 4096 * 1024);
  transpose_to_bf16<<<dim3(96, 32), 256, 0, stream>>>(W_qkv, wqkvT, 1024, 3072);
  transpose_to_bf16<<<dim3(32, 32), 256, 0, stream>>>(W_proj, wprojT, 1024, 1024);
  gemm_bt<1><<<dim3(32, 24), 256, 0, stream>>>(xb, wqkvT, (void*)qkb, vtb, nullptr, 4096, 3072, 1024);
  diff_attn<<<dim3(32, 16, 2), 256, 0, stream>>>(qkb, vtb, ob, lq1, lk1, lq2, lk2, subln);
  gemm_bt<0><<<dim3(32, 8), 256, 0, stream>>>(ob, wprojT, d_out, nullptr, b_proj, 4096, 1024, 1024);
}

// Round 11
// 171.694 us; speedup vs baseline: 1.7993x; 1.1988x over previous
//
#include <hip/hip_runtime.h>

typedef unsigned short ushort_t;
typedef unsigned int uint_t;
typedef __attribute__((ext_vector_type(4))) float f32x4;
typedef __attribute__((ext_vector_type(8))) __bf16 bf16x8;

#define LAMBDA_INIT 0.7836057665316245f
#define ONE_MINUS_LI 0.21639423346837552f
#define QSCALE_LOG2E 0.25505654442552663f  // 32^-0.5 * log2(e)

__device__ inline ushort_t f2bf(float f) {
  union { float f; unsigned u; } v; v.f = f;
  unsigned r = (v.u + 0x7FFFu + ((v.u >> 16) & 1u)) >> 16;
  return (ushort_t)r;
}

// bare v_exp_f32 (args bounded, no libm range fixup needed)
__device__ inline float fexp2(float x) {
  float r;
  asm("v_exp_f32 %0, %1" : "=v"(r) : "v"(x));
  return r;
}

// pack 2 f32 -> 2 bf16 (RNE), lo in low half
__device__ inline uint_t cvtpk(float lo, float hi) {
  uint_t r;
  asm("v_cvt_pk_bf16_f32 %0, %1, %2" : "=v"(r) : "v"(lo), "v"(hi));
  return r;
}

__device__ inline f32x4 zero4() { f32x4 z = {0.f, 0.f, 0.f, 0.f}; return z; }

__device__ inline f32x4 mfma16(bf16x8 a, bf16x8 b, f32x4 c) {
  return __builtin_amdgcn_mfma_f32_16x16x32_bf16(a, b, c, 0, 0, 0);
}

__device__ inline void gload_lds16(const void* g, void* l) {
  __builtin_amdgcn_global_load_lds(
      (const __attribute__((address_space(1))) unsigned int*)g,
      (__attribute__((address_space(3))) unsigned int*)l, 16, 0, 0);
}

// ---------------- convert x (fp32 -> bf16) ----------------
__global__ __launch_bounds__(256) void cvt_f32_bf16(const float* __restrict__ in,
                                                    ushort_t* __restrict__ out, int n) {
  int i = (blockIdx.x * 256 + threadIdx.x) * 8;
  if (i >= n) return;
  float4 a = *(const float4*)(in + i);
  float4 b = *(const float4*)(in + i + 4);
  uint4 pack;
  pack.x = cvtpk(a.x, a.y);
  pack.y = cvtpk(a.z, a.w);
  pack.z = cvtpk(b.x, b.y);
  pack.w = cvtpk(b.z, b.w);
  *(uint4*)(out + i) = pack;
}

// ---------------- transpose W (KxN fp32) -> WT (NxK bf16) ----------------
__global__ __launch_bounds__(256) void transpose_to_bf16(const float* __restrict__ W,
                                                         ushort_t* __restrict__ WT,
                                                         int K, int N) {
  __shared__ float tile[32][33];
  int n0 = blockIdx.x * 32, k0 = blockIdx.y * 32;
  int tx = threadIdx.x & 31, ty = threadIdx.x >> 5;
#pragma unroll
  for (int j = 0; j < 4; ++j) {
    int k = k0 + ty + j * 8;
    tile[ty + j * 8][tx] = W[(size_t)k * N + n0 + tx];
  }
  __syncthreads();
#pragma unroll
  for (int j = 0; j < 4; ++j) {
    int n = n0 + ty + j * 8;
    WT[(size_t)n * K + k0 + tx] = f2bf(tile[tx][ty + j * 8]);
  }
}

// ---------------- GEMM: C[M,N] = A[M,K] * Bt[N,K]^T, bf16 in ----------------
// XCD-aware block swizzle: XCD r hosts contiguous col-panels -> B reuse in L2.
template <int MODE>
__global__ __launch_bounds__(256) void gemm_bt(const ushort_t* __restrict__ A,
                                               const ushort_t* __restrict__ Bt,
                                               void* __restrict__ C,
                                               ushort_t* __restrict__ vt_out,
                                               const float* __restrict__ bias,
                                               int M, int N, int K) {
  __shared__ ushort_t As[128 * 32];
  __shared__ ushort_t Bs[128 * 32];
  const int tid = threadIdx.x;
  const int wave = tid >> 6, lane = tid & 63;
  const int wr = wave >> 1, wc = wave & 1;
  const int lg = lane >> 4, ll = lane & 15;

  // XCD swizzle (nwg divisible by 8: 768 and 256)
  const int lin = blockIdx.x + gridDim.x * blockIdx.y;
  const int cpx = (gridDim.x * gridDim.y) >> 3;
  const int swz = (lin & 7) * cpx + (lin >> 3);
  const int row0 = (swz % gridDim.x) * 128, col0 = (swz / gridDim.x) * 128;

  f32x4 acc[4][4];
#pragma unroll
  for (int m = 0; m < 4; ++m)
#pragma unroll
    for (int n = 0; n < 4; ++n) acc[m][n] = zero4();

  for (int k0 = 0; k0 < K; k0 += 32) {
    __syncthreads();
#pragma unroll
    for (int i = 0; i < 2; ++i) {
      int c = tid + i * 256;
      int r = c >> 2, ko = (c & 3) << 3;
      gload_lds16(A + (size_t)(row0 + r) * K + k0 + ko,
                  (char*)As + (size_t)(wave * 64 + i * 256) * 16);
      gload_lds16(Bt + (size_t)(col0 + r) * K + k0 + ko,
                  (char*)Bs + (size_t)(wave * 64 + i * 256) * 16);
    }
    __syncthreads();
    bf16x8 af[4], bf[4];
#pragma unroll
    for (int m = 0; m < 4; ++m)
      af[m] = *(const bf16x8*)(As + (wr * 64 + m * 16 + ll) * 32 + (lg << 3));
#pragma unroll
    for (int n = 0; n < 4; ++n)
      bf[n] = *(const bf16x8*)(Bs + (wc * 64 + n * 16 + ll) * 32 + (lg << 3));
#pragma unroll
    for (int m = 0; m < 4; ++m)
#pragma unroll
      for (int n = 0; n < 4; ++n) acc[m][n] = mfma16(af[m], bf[n], acc[m][n]);
  }

#pragma unroll
  for (int m = 0; m < 4; ++m) {
#pragma unroll
    for (int n = 0; n < 4; ++n) {
      int gc = col0 + wc * 64 + n * 16 + ll;
      int gr0 = row0 + wr * 64 + m * 16 + (lg << 2);
      if (MODE == 0) {
#pragma unroll
        for (int j = 0; j < 4; ++j)
          ((float*)C)[(size_t)(gr0 + j) * N + gc] = acc[m][n][j] + bias[gc];
      } else {
        if (gc < 2048) {
          float sc = (gc < 1024) ? QSCALE_LOG2E : 1.0f;
#pragma unroll
          for (int j = 0; j < 4; ++j)
            ((ushort_t*)C)[(size_t)(gr0 + j) * 2048 + gc] = f2bf(acc[m][n][j] * sc);
        } else {
          // V columns -> transposed store, 4 consecutive n packed into 8B
          int hv = (gc - 2048) >> 6, dv = (gc - 2048) & 63;
          int bb = gr0 >> 11, nn = gr0 & 2047;
          uint2 w;
          w.x = cvtpk(acc[m][n][0], acc[m][n][1]);
          w.y = cvtpk(acc[m][n][2], acc[m][n][3]);
          *(uint2*)(vt_out + ((size_t)((bb * 16 + hv) * 64 + dv)) * 2048 + nn) = w;
        }
      }
    }
  }
}

// ---------------- differential flash attention (swapped-QK, static max, dbuf) ----------------
// Proven R4 kernel, byte-identical compute; only the block-index decode is
// XCD-swizzled so all 32 qt-blocks sharing one (b,h)'s K/V panels land on the
// SAME XCD (4 heads x 512KB = 2MB per 4MB L2) instead of replicating panels
// into all 8 L2s (R4 FETCH_SIZE 69.7MB vs ~24MB ideal).
__global__ __launch_bounds__(256) void diff_attn(const ushort_t* __restrict__ qk,
                                                 const ushort_t* __restrict__ vt,
                                                 ushort_t* __restrict__ o,
                                                 const float* __restrict__ lq1,
                                                 const float* __restrict__ lk1,
                                                 const float* __restrict__ lq2,
                                                 const float* __restrict__ lk2,
                                                 const float* __restrict__ subln) {
  const int lin = blockIdx.x + (blockIdx.y << 5) + (blockIdx.z << 9);
  const int swz = ((lin & 7) << 7) + (lin >> 3);    // XCD r -> swz in [128r, 128r+128)
  const int qt = swz & 31, h = (swz >> 5) & 15, b = swz >> 9;
  const int tid = threadIdx.x, wave = tid >> 6, lane = tid & 63;
  const int lg = lane >> 4, ll = lane & 15;

  const size_t qbase = (size_t)b * 2048 * 2048;
  const int cq1 = (h << 5), cq2 = 512 + (h << 5);
  const int ck1 = 1024 + (h << 5), ck2 = 1536 + (h << 5);
  const size_t vbase = (size_t)((b * 16 + h) * 64) * 2048;

  float sl1 = 0.f, sl2 = 0.f;
  for (int j = 0; j < 32; ++j) { sl1 += lq1[j] * lk1[j]; sl2 += lq2[j] * lk2[j]; }
  const float lam = __expf(sl1) - __expf(sl2) + LAMBDA_INIT;

  __shared__ ushort_t Ks[2][64 * 64];   // [kv r][8 chunks: 0-3 K1, 4-7 K2], XOR-8 swizzled
  __shared__ ushort_t Vs[2][64 * 64];   // [d r][8 t-chunks], XOR-8 swizzled
  __shared__ ushort_t Pl[4][16 * 72];   // per-wave P, padded stride 72

  // Q fragments (B-operand of swapped QK^T)
  const int qrow = qt * 64 + wave * 16 + ll;
  const bf16x8 q1f = *(const bf16x8*)(qk + qbase + (size_t)qrow * 2048 + cq1 + (lg << 3));
  const bf16x8 q2f = *(const bf16x8*)(qk + qbase + (size_t)qrow * 2048 + cq2 + (lg << 3));

  f32x4 o1[4], o2[4];
#pragma unroll
  for (int nb = 0; nb < 4; ++nb) { o1[nb] = zero4(); o2[nb] = zero4(); }
  float l1p = 0.f, l2p = 0.f;
  ushort_t* Pw = &Pl[wave][0];

  // staging geometry: slot s -> row r = s>>3, lds chunk s&7 holds global chunk (s&7)^(r&7)
  const int s0 = tid, s1 = tid + 256;
  const int r0 = s0 >> 3, c0 = (s0 & 7) ^ (r0 & 7);
  const int r1 = s1 >> 3, c1 = (s1 & 7) ^ (r1 & 7);
  const int kc0 = ((c0 & 4) ? ck2 : ck1) + ((c0 & 3) << 3);
  const int kc1 = ((c1 & 4) ? ck2 : ck1) + ((c1 & 3) << 3);
  const int ub0 = (wave << 6) * 16;
  const int ub1 = ((wave << 6) + 256) * 16;

#define STAGE(buf, kv0)                                                                   \
  do {                                                                                    \
    gload_lds16(qk + qbase + (size_t)((kv0) + r0) * 2048 + kc0, (char*)Ks[buf] + ub0);    \
    gload_lds16(qk + qbase + (size_t)((kv0) + r1) * 2048 + kc1, (char*)Ks[buf] + ub1);    \
    gload_lds16(vt + vbase + (size_t)r0 * 2048 + (kv0) + (c0 << 3), (char*)Vs[buf] + ub0);\
    gload_lds16(vt + vbase + (size_t)r1 * 2048 + (kv0) + (c1 << 3), (char*)Vs[buf] + ub1);\
  } while (0)

  auto compute_tile = [&](const ushort_t* Kc, const ushort_t* Vc) {
    bf16x8 vf[2][4];
#pragma unroll
    for (int ks = 0; ks < 2; ++ks)
#pragma unroll
      for (int nb = 0; nb < 4; ++nb)
        vf[ks][nb] = *(const bf16x8*)(Vc + nb * 1024 + ll * 64 + (((ks * 4 + lg) ^ (ll & 7)) << 3));
#pragma unroll
    for (int pass = 0; pass < 2; ++pass) {
      const int cK = (lg ^ (ll & 7)) ^ (pass << 2);
      bf16x8 kf[4];
#pragma unroll
      for (int nb = 0; nb < 4; ++nb)
        kf[nb] = *(const bf16x8*)(Kc + nb * 1024 + ll * 64 + (cK << 3));
      const bf16x8 qf = pass ? q2f : q1f;
      f32x4* oacc = pass ? o2 : o1;
      f32x4 s[4];
#pragma unroll
      for (int nb = 0; nb < 4; ++nb)
        s[nb] = mfma16(kf[nb], qf, zero4());   // D: row=k (4lg+i), col=q (ll)
      float part = 0.f;
#pragma unroll
      for (int nb = 0; nb < 4; ++nb) {
        float e0 = fexp2(s[nb][0]), e1 = fexp2(s[nb][1]);
        float e2 = fexp2(s[nb][2]), e3 = fexp2(s[nb][3]);
        part += (e0 + e1) + (e2 + e3);
        uint2 w;
        w.x = cvtpk(e0, e1);
        w.y = cvtpk(e2, e3);
        // P[q=ll][k = nb*16 + 4lg .. +3]
        *(uint2*)(Pw + ll * 72 + nb * 16 + (lg << 2)) = w;
      }
      if (pass) l2p += part; else l1p += part;
#pragma unroll
      for (int ks = 0; ks < 2; ++ks) {
        bf16x8 pf = *(const bf16x8*)(Pw + ll * 72 + ks * 32 + (lg << 3));
#pragma unroll
        for (int nb = 0; nb < 4; ++nb) oacc[nb] = mfma16(pf, vf[ks][nb], oacc[nb]);
      }
    }
  };

  STAGE(0, 0);
  __syncthreads();
  for (int tt = 0; tt < 16; ++tt) {
    STAGE(1, (tt * 2 + 1) * 64);
    compute_tile(Ks[0], Vs[0]);
    __syncthreads();
    if (tt < 15) STAGE(0, (tt * 2 + 2) * 64);
    compute_tile(Ks[1], Vs[1]);
    __syncthreads();
  }
#undef STAGE

  // l lives per-lane for q = ll; finish reduction over lg, then fetch per-row.
  float l1 = l1p; l1 += __shfl_xor(l1, 16); l1 += __shfl_xor(l1, 32);
  float l2 = l2p; l2 += __shfl_xor(l2, 16); l2 += __shfl_xor(l2, 32);
  float i1[4], i2[4];
#pragma unroll
  for (int j = 0; j < 4; ++j) {
    int src = (lane & 48) | ((lg << 2) + j);   // lane with ll == q-row
    i1[j] = 1.f / __shfl(l1, src);
    i2[j] = 1.f / __shfl(l2, src);
  }

  float ss[4] = {0.f, 0.f, 0.f, 0.f};
  f32x4 ov[4];
#pragma unroll
  for (int nb = 0; nb < 4; ++nb) {
#pragma unroll
    for (int j = 0; j < 4; ++j) {
      float x = o1[nb][j] * i1[j] - lam * (o2[nb][j] * i2[j]);
      ov[nb][j] = x;
      ss[j] += x * x;
    }
  }
#pragma unroll
  for (int mask = 1; mask < 16; mask <<= 1)
#pragma unroll
    for (int j = 0; j < 4; ++j) ss[j] += __shfl_xor(ss[j], mask);
  float nf[4];
#pragma unroll
  for (int j = 0; j < 4; ++j) nf[j] = rsqrtf(ss[j] * (1.f / 64.f) + 1e-5f);
  const size_t orow0 = (size_t)(b * 2048 + qt * 64 + wave * 16);
#pragma unroll
  for (int nb = 0; nb < 4; ++nb) {
    int d = nb * 16 + ll;
    float sw = subln[d] * ONE_MINUS_LI;
#pragma unroll
    for (int j = 0; j < 4; ++j) {
      int r = (lg << 2) + j;
      o[(orow0 + r) * 1024 + (h << 6) + d] = f2bf(ov[nb][j] * nf[j] * sw);
    }
  }
}

extern "C" void kernel_launch(void* const* d_in, const int* in_sizes, int n_in,
                              void* d_out, int out_size, void* d_ws, size_t ws_size,
                              hipStream_t stream) {
  const float* x      = (const float*)d_in[0];
  const float* W_qkv  = (const float*)d_in[1];
  const float* W_proj = (const float*)d_in[2];
  const float* b_proj = (const float*)d_in[3];
  const float* lq1    = (const float*)d_in[4];
  const float* lk1    = (const float*)d_in[5];
  const float* lq2    = (const float*)d_in[6];
  const float* lk2    = (const float*)d_in[7];
  const float* subln  = (const float*)d_in[8];

  char* ws = (char*)d_ws;
  ushort_t* xb     = (ushort_t*)(ws);                 //  8,388,608 B (4096x1024 bf16)
  ushort_t* qkb    = (ushort_t*)(ws + 8388608);       // 16,777,216 B (4096x2048 bf16, q|k)
  ushort_t* vtb    = (ushort_t*)(ws + 25165824);      //  8,388,608 B (V^T: [2*16*64][2048])
  ushort_t* wqkvT  = (ushort_t*)(ws + 33554432);      //  6,291,456 B (3072x1024 bf16)
  ushort_t* wprojT = (ushort_t*)(ws + 39845888);      //  2,097,152 B (1024x1024 bf16)
  ushort_t* ob     = (ushort_t*)(ws + 41943040);      //  8,388,608 B (4096x1024 bf16)

  cvt_f32_bf16<<<2048, 256, 0, stream>>>(x, xb, 4096 * 1024);
  transpose_to_bf16<<<dim3(96, 32), 256, 0, stream>>>(W_qkv, wqkvT, 1024, 3072);
  transpose_to_bf16<<<dim3(32, 32), 256, 0, stream>>>(W_proj, wprojT, 1024, 1024);
  gemm_bt<1><<<dim3(32, 24), 256, 0, stream>>>(xb, wqkvT, (void*)qkb, vtb, nullptr, 4096, 3072, 1024);
  diff_attn<<<dim3(32, 16, 2), 256, 0, stream>>>(qkb, vtb, ob, lq1, lk1, lq2, lk2, subln);
  gemm_bt<0><<<dim3(32, 8), 256, 0, stream>>>(ob, wprojT, d_out, nullptr, b_proj, 4096, 1024, 1024);
}